// Round 8
// baseline (229.624 us; speedup 1.0000x reference)
//
#include <hip/hip_runtime.h>
#include <hip/hip_bf16.h>

// MC3DAD kNN(k=5) covariance-trace curvature. B=8, N=4096, f32.
// Round 8: outward positional sweep. Points x-binned (256 exact-pow2 bins)
// and stored sorted-by-bin; each query's 8 lanes (4 right + 4 left,
// interleave stride 4) sweep outward from the query's own sorted position,
// so near-best candidates come first and tau collapses within ~10 steps
// (fixes r7's per-lane warm-up fragmentation). Per-lane exact termination:
// same-bin x-spread < W  =>  all later positions have dx >= (cx-qx)-W, so
// stop when (sgn*(cx-qx)-W)^2 >= tau+1e-3. No strip table in the hot loop.
// Proven-verbatim machinery: inflated-tau fmaf filter (margin 1e-4), exact
// rn-tree dd recompute, u64 keys (bits(max(dd,0))<<32 | oidx<<16 | pos)
// via strict-< min/max network, butterfly tau-share + key-merge over masks
// 8/16/32, sqrt-rerank by (dist, oidx), r1 covariance tree, r2 curvature.

typedef unsigned long long ull;
typedef unsigned short u16;
typedef unsigned int u32;

constexpr int   N_PTS  = 4096;
constexpr int   BATCH  = 8;
constexpr int   KNN    = 5;
constexpr int   NSTRIP = 256;
constexpr float XMIN   = -8.0f;
constexpr float STRIPW = 0.0625f;      // 16/256, exact in fp32
constexpr float INVW   = 16.0f;        // exact pow2: binning is exact
constexpr int   NTHR   = 256;          // 4 waves, 32 queries per block
constexpr float FILT_MARGIN = 1e-4f;   // fast-filter false-reject slack
constexpr float TERM_SLACK  = 1e-3f;   // termination slack (>> fp32 tree err)

__device__ __forceinline__ ull umin64(ull a, ull b) { return a < b ? a : b; }
__device__ __forceinline__ ull umax64(ull a, ull b) { return a < b ? b : a; }

// Merge two ascending sorted 5-lists (u64 lex keys) -> ascending bottom-5.
__device__ __forceinline__ void merge5(ull a[KNN], const ull b[KNN])
{
    const ull r0 = umin64(a[0], b[0]);
    const ull r1 = umin64(umin64(a[1], b[1]), umax64(a[0], b[0]));
    const ull r2 = umin64(umin64(a[2], b[2]),
                          umin64(umax64(a[1], b[0]), umax64(a[0], b[1])));
    const ull r3 = umin64(umin64(a[3], b[3]),
                   umin64(umax64(a[2], b[0]),
                   umin64(umax64(a[1], b[1]), umax64(a[0], b[2]))));
    const ull r4 = umin64(umin64(a[4], b[4]),
                   umin64(umin64(umax64(a[3], b[0]), umax64(a[2], b[1])),
                          umin64(umax64(a[1], b[2]), umax64(a[0], b[3]))));
    a[0] = r0; a[1] = r1; a[2] = r2; a[3] = r3; a[4] = r4;
}

// ---------------- K1: counting sort into 256 x-bins (r5 structure) ----------------
__global__ __launch_bounds__(256)
void build_kernel(const float* __restrict__ pcd, float4* __restrict__ spts,
                  u16* __restrict__ sidx)
{
    __shared__ u32 hist[NSTRIP];
    __shared__ u32 cur[NSTRIP];
    const int b = blockIdx.x;
    const int t = threadIdx.x;
    const float* __restrict__ batch = pcd + (size_t)b * N_PTS * 3;

    hist[t] = 0;
    __syncthreads();

    float px[16], py[16], pz[16]; int ps[16];
    #pragma unroll
    for (int i = 0; i < 16; ++i) {
        const int p = t + i * 256;
        const float x = batch[p * 3 + 0];
        const float y = batch[p * 3 + 1];
        const float z = batch[p * 3 + 2];
        px[i] = x; py[i] = y; pz[i] = z;
        int s = (int)floorf((x - XMIN) * INVW);
        s = s < 0 ? 0 : (s > NSTRIP - 1 ? NSTRIP - 1 : s);
        ps[i] = s;
        atomicAdd(&hist[s], 1u);
    }
    __syncthreads();
    for (int off = 1; off < NSTRIP; off <<= 1) {     // inclusive scan, 256 bins
        u32 v = 0;
        if (t >= off) v = hist[t - off];
        __syncthreads();
        hist[t] += v;
        __syncthreads();
    }
    cur[t] = (t == 0) ? 0u : hist[t - 1];
    __syncthreads();

    float4* __restrict__ bp = spts + (size_t)b * N_PTS;
    u16*    __restrict__ bi = sidx + (size_t)b * N_PTS;
    #pragma unroll
    for (int i = 0; i < 16; ++i) {
        const int p = t + i * 256;
        const u32 pos = atomicAdd(&cur[ps[i]], 1u);
        const float x = px[i], y = py[i], z = pz[i];
        const float w = __fadd_rn(__fadd_rn(__fmul_rn(x, x), __fmul_rn(y, y)),
                                  __fmul_rn(z, z));            // exact |p|^2 tree
        bp[pos] = make_float4(x, y, z, w);
        bi[pos] = (u16)p;
    }
}

// ---------------- K2: outward-sweep exact kNN + trace ----------------
__global__ __launch_bounds__(NTHR)
void knn_kernel(const float* __restrict__ pcd, const float4* __restrict__ spts,
                const u16* __restrict__ sidx, float* __restrict__ trace_out)
{
    const int b    = blockIdx.y;
    const int t    = threadIdx.x;
    const int lane = t & 63;
    const int wave = t >> 6;
    const int qi   = lane & 7;             // query within wave
    const int seg  = lane >> 3;            // 0..3 right, 4..7 left
    const bool right = seg < 4;
    const int  sub   = seg & 3;

    const float4* __restrict__ bp    = spts + (size_t)b * N_PTS;
    const u16*    __restrict__ bi    = sidx + (size_t)b * N_PTS;
    const float*  __restrict__ batch = pcd  + (size_t)b * N_PTS * 3;

    const int qs = blockIdx.x * 32 + wave * 8 + qi;
    const float4 q4 = bp[qs];
    const float qx = q4.x, qy = q4.y, qz = q4.z, qw = q4.w;

    int p = right ? qs + sub : qs - 1 - sub;   // seg0 stream includes self
    const int   stp = right ? 4 : -4;
    const float sgn = right ? 1.0f : -1.0f;

    float tau  = __builtin_inff();
    float tauf = __builtin_inff();

    ull key[KNN];
    #pragma unroll
    for (int r = 0; r < KNN; ++r) key[r] = 0x7f800000ffffffffULL;  // (+inf, ~0)

    // exact rn-tree insert from registers; no-op lanes push all-ones
    auto insert_exact = [&](const float4 c, u32 oi, int pos, bool keep) {
        const float dot = __fadd_rn(__fadd_rn(__fmul_rn(qx, c.x),
                                              __fmul_rn(qy, c.y)),
                                    __fmul_rn(qz, c.z));
        const float dd  = __fsub_rn(__fadd_rn(qw, c.w), __fmul_rn(2.0f, dot));
        const float ddk = fmaxf(dd, 0.0f);                    // ref: max(d2,0)
        ull a = keep ? (((ull)__float_as_uint(ddk) << 32) | (oi << 16) | (u32)pos)
                     : 0xffffffffffffffffULL;
        #pragma unroll
        for (int r = 0; r < KNN; ++r) {                       // strict-< insert
            const ull lo = umin64(a, key[r]);
            const ull hi = umax64(a, key[r]);
            key[r] = lo; a = hi;
        }
    };

    auto share_tau = [&]() {
        tau = fminf(tau, __uint_as_float((u32)(key[KNN - 1] >> 32)));
        #pragma unroll
        for (int mask = 8; mask < 64; mask <<= 1)
            tau = fminf(tau, __shfl_xor(tau, mask));          // same-query min
        tauf = tau - qw + FILT_MARGIN;
    };

    bool alive = (u32)p < (u32)N_PTS;

    while (__any(alive)) {
        const int p1 = p, p2 = p + stp;
        const bool v1 = alive && ((u32)p1 < (u32)N_PTS);
        const bool v2 = alive && ((u32)p2 < (u32)N_PTS);
        const int a1 = v1 ? p1 : qs;
        const int a2 = v2 ? p2 : qs;
        const float4 c1 = bp[a1];
        const float4 c2 = bp[a2];
        const float t21 = fmaf(-2.0f, fmaf(qx, c1.x, fmaf(qy, c1.y, qz * c1.z)),
                               c1.w);
        const float t22 = fmaf(-2.0f, fmaf(qx, c2.x, fmaf(qy, c2.y, qz * c2.z)),
                               c2.w);
        const bool k1 = v1 && (t21 < tauf);
        const bool k2 = v2 && (t22 < tauf);
        if (__any(k1 || k2)) {
            const u32 o1 = bi[a1];
            const u32 o2 = bi[a2];
            insert_exact(c1, o1, a1, k1);
            insert_exact(c2, o2, a2, k2);
            share_tau();
        }
        // per-lane exact termination on the farthest valid candidate:
        // all later positions on this side have dx >= (cx - qx)*sgn - W
        {
            const float cxf = v2 ? c2.x : c1.x;
            const float gm = fmaf(sgn, cxf - qx, -STRIPW);
            if ((v1 || v2) && gm > 0.0f &&
                gm * gm >= tau + TERM_SLACK) alive = false;
        }
        p += 2 * stp;
        alive = alive && ((u32)p < (u32)N_PTS);
    }

    // ---- butterfly key merge across the 8 same-query lanes ----
    #pragma unroll
    for (int mask = 8; mask < 64; mask <<= 1) {
        ull o[KNN];
        #pragma unroll
        for (int r = 0; r < KNN; ++r) o[r] = __shfl_xor(key[r], mask);
        merge5(key, o);
    }

    // ---- epilogue on seg==0 lanes: sqrt-rerank, centroid, cov trace ----
    if (seg == 0) {
        ull k2s[KNN];
        #pragma unroll
        for (int r = 0; r < KNN; ++r) {
            const float dd = __uint_as_float((u32)(key[r] >> 32));
            const float dist = __fsqrt_rn(dd);                // dd >= 0 already
            k2s[r] = ((ull)__float_as_uint(dist) << 32) | (key[r] & 0xffffffffULL);
        }
        #pragma unroll
        for (int i = 0; i < KNN - 1; ++i)                     // bubble by (dist,oidx)
            #pragma unroll
            for (int r = 0; r < KNN - 1 - i; ++r) {
                const ull lo2 = umin64(k2s[r], k2s[r + 1]);
                const ull hi2 = umax64(k2s[r], k2s[r + 1]);
                k2s[r] = lo2; k2s[r + 1] = hi2;
            }

        float nx[KNN], ny[KNN], nz[KNN];
        #pragma unroll
        for (int r = 0; r < KNN; ++r) {
            const int sel = (int)((k2s[r] >> 16) & 0xffffULL); // orig idx payload
            nx[r] = batch[sel * 3 + 0];
            ny[r] = batch[sel * 3 + 1];
            nz[r] = batch[sel * 3 + 2];
        }
        float sx = nx[0], sy = ny[0], sz = nz[0];
        #pragma unroll
        for (int r = 1; r < KNN; ++r) {
            sx = __fadd_rn(sx, nx[r]);
            sy = __fadd_rn(sy, ny[r]);
            sz = __fadd_rn(sz, nz[r]);
        }
        const float cx = __fdiv_rn(sx, 5.0f);
        const float cy = __fdiv_rn(sy, 5.0f);
        const float cz = __fdiv_rn(sz, 5.0f);

        float sxx = 0.0f, syy = 0.0f, szz = 0.0f;
        #pragma unroll
        for (int r = 0; r < KNN; ++r) {
            const float dx = __fsub_rn(nx[r], cx);
            const float dy = __fsub_rn(ny[r], cy);
            const float dz = __fsub_rn(nz[r], cz);
            sxx = __fadd_rn(sxx, __fmul_rn(dx, dx));
            syy = __fadd_rn(syy, __fmul_rn(dy, dy));
            szz = __fadd_rn(szz, __fmul_rn(dz, dz));
        }
        const float trace = __fadd_rn(__fadd_rn(__fmul_rn(sxx, 0.25f),
                                                __fmul_rn(syy, 0.25f)),
                                      __fmul_rn(szz, 0.25f));
        trace_out[(size_t)b * N_PTS + bi[qs]] = trace;
    }
}

// ---------------- K3: r2-proven curvature (trace in ws -> d_out) ----------------
__global__ __launch_bounds__(256)
void curvature_kernel(const float* __restrict__ trace, float* __restrict__ out)
{
    __shared__ float red[256];
    const int b = blockIdx.x >> 3;
    const int c = blockIdx.x & 7;
    const int t = threadIdx.x;
    const float* __restrict__ tr = trace + (size_t)b * N_PTS;

    float s = 0.0f;
    #pragma unroll
    for (int i = 0; i < 16; ++i)
        s += tr[t + i * 256];
    red[t] = s;
    __syncthreads();
    #pragma unroll
    for (int o = 128; o > 0; o >>= 1) {
        if (t < o) red[t] += red[t + o];
        __syncthreads();
    }
    const float denom = red[0] + 1e-8f;

    float* __restrict__ ob = out + (size_t)b * N_PTS;
    const int x = c * 512 + t;
    ob[x]       = tr[x]       / denom;
    ob[x + 256] = tr[x + 256] / denom;
}

extern "C" void kernel_launch(void* const* d_in, const int* in_sizes, int n_in,
                              void* d_out, int out_size, void* d_ws, size_t ws_size,
                              hipStream_t stream)
{
    (void)in_sizes; (void)n_in; (void)out_size; (void)ws_size;
    const float* pcd = (const float*)d_in[0];   // [8,4096,3] f32
    float* out = (float*)d_out;                 // [8,4096] f32

    char* w = (char*)d_ws;
    float4* spts  = (float4*)w;                         // 512 KB
    u16*    sidxp = (u16*)(w + 524288);                 // 64 KB
    float*  trace = (float*)(w + 524288 + 65536);       // 128 KB

    build_kernel<<<BATCH, 256, 0, stream>>>(pcd, spts, sidxp);
    dim3 g2(N_PTS / 32, BATCH);                         // 128 x 8 = 1024 blocks
    knn_kernel<<<g2, NTHR, 0, stream>>>(pcd, spts, sidxp, trace);
    curvature_kernel<<<BATCH * 8, 256, 0, stream>>>(trace, out);
}